// Round 19
// baseline (422.743 us; speedup 1.0000x reference)
//
#include <hip/hip_runtime.h>
#include <cstdint>
#include <cstddef>

#define N_NODES_C 100000
#define N_EDGES_C 1600000
#define LN_EPS_C 1e-5f
#define CLAMP_C 1.8f
#define LN_BLOCKS 1024
// Radix-binned scatter: bin = row >> 10 (1024 rows/bin), 98 bins.
// Staging layout is CSR-aligned (bincur init = rowstart at bin boundaries).
#define BINS 98
#define CHUNK 4096
#define EPT 16
#define NCHUNK 391  // ceil(1.6M / 4096)

typedef unsigned short ushort_t;

__device__ __forceinline__ float readlane_f(float v, int l) {
  return __uint_as_float(__builtin_amdgcn_readlane(__float_as_uint(v), l));
}

__device__ __forceinline__ float wave_sum(float v) {
#pragma unroll
  for (int off = 32; off > 0; off >>= 1) v += __shfl_xor(v, off, 64);
  return v;
}

// bf16 pack (round-to-nearest-even) / unpack
__device__ __forceinline__ ushort_t f2bf(float f) {
  unsigned u = __float_as_uint(f);
  unsigned r = (u + 0x7fffu + ((u >> 16) & 1u)) >> 16;
  return (ushort_t)r;
}
__device__ __forceinline__ float bf2f(ushort_t u) {
  return __uint_as_float((unsigned)u << 16);
}

// ---------------- CSR build ----------------
__global__ __launch_bounds__(256) void hist_kernel(const int* __restrict__ row,
                                                   int* __restrict__ counts) {
  int tid = blockIdx.x * blockDim.x + threadIdx.x;
  int nt = gridDim.x * blockDim.x;
  int r[8];
#pragma unroll
  for (int k = 0; k < 8; ++k) {
    int e = tid + k * nt;
    r[k] = (e < N_EDGES_C) ? row[e] : -1;
  }
#pragma unroll
  for (int k = 0; k < 8; ++k)
    if (r[k] >= 0) atomicAdd(&counts[r[k]], 1);
}

__global__ void scan1_kernel(const int* __restrict__ counts, int* __restrict__ rowstart,
                             int* __restrict__ bsums) {
  __shared__ int lds[256];
  int t = threadIdx.x;
  int base = blockIdx.x * 1024 + t * 4;
  int c0 = (base + 0 < N_NODES_C) ? counts[base + 0] : 0;
  int c1 = (base + 1 < N_NODES_C) ? counts[base + 1] : 0;
  int c2 = (base + 2 < N_NODES_C) ? counts[base + 2] : 0;
  int c3 = (base + 3 < N_NODES_C) ? counts[base + 3] : 0;
  int s = c0 + c1 + c2 + c3;
  lds[t] = s;
  __syncthreads();
#pragma unroll
  for (int off = 1; off < 256; off <<= 1) {
    int v = (t >= off) ? lds[t - off] : 0;
    __syncthreads();
    lds[t] += v;
    __syncthreads();
  }
  int incl = lds[t];
  int excl = incl - s;
  if (t == 255) bsums[blockIdx.x] = incl;
  if (base + 0 < N_NODES_C) rowstart[base + 0] = excl;
  excl += c0;
  if (base + 1 < N_NODES_C) rowstart[base + 1] = excl;
  excl += c1;
  if (base + 2 < N_NODES_C) rowstart[base + 2] = excl;
  excl += c2;
  if (base + 3 < N_NODES_C) rowstart[base + 3] = excl;
}

__global__ void scan2_kernel(int* __restrict__ bsums, int nb) {
  __shared__ int lds[128];
  int t = threadIdx.x;
  int v = (t < nb) ? bsums[t] : 0;
  lds[t] = v;
  __syncthreads();
#pragma unroll
  for (int off = 1; off < 128; off <<= 1) {
    int u = (t >= off) ? lds[t - off] : 0;
    __syncthreads();
    lds[t] += u;
    __syncthreads();
  }
  if (t < nb) bsums[t] = lds[t] - v;
}

// final rowstart + cursor copy + per-bin staging cursors (CSR-aligned)
__global__ void scan3_kernel(int* __restrict__ rowstart, int* __restrict__ cursor,
                             int* __restrict__ bincur, const int* __restrict__ bsums) {
  int add = bsums[blockIdx.x];
  int base = blockIdx.x * 1024 + threadIdx.x * 4;
#pragma unroll
  for (int i = 0; i < 4; ++i) {
    int rI = base + i;
    if (rI < N_NODES_C) {
      int v = rowstart[rI] + add;
      rowstart[rI] = v;
      cursor[rI] = v;
      if ((rI & 1023) == 0) bincur[rI >> 10] = v;
    }
  }
}

// ---------------- Pass A: block-local radix partition into bin-ordered staging
// Each block: 4096-edge chunk -> LDS hist(98) -> scan -> LDS reorder -> one
// global range reservation per bin -> copy-out as ~42-record sequential runs
// per bin (full-line stores). Staging is CSR-aligned; stage_r carries the
// full row id so pass B needs no bin arithmetic.
__global__ __launch_bounds__(256) void partition_kernel(
    const int* __restrict__ row, const int* __restrict__ col,
    const float* __restrict__ vals, int* __restrict__ bincur,
    int2* __restrict__ stage_cv, int* __restrict__ stage_r) {
  __shared__ int hist[128];
  __shared__ int scanarr[128];
  __shared__ int cnt2[128];
  __shared__ int basearr[128];
  __shared__ int2 s_cv[CHUNK];
  __shared__ int s_r[CHUNK];
  __shared__ unsigned char s_bin[CHUNK];
  int t = threadIdx.x;
  int e0 = blockIdx.x * CHUNK;
  if (t < 128) {
    hist[t] = 0;
    cnt2[t] = 0;
    basearr[t] = 0;
  }
  __syncthreads();
  int rr[EPT], cc[EPT], bn[EPT];
  float vv[EPT];
#pragma unroll
  for (int k = 0; k < EPT; ++k) {
    int e = e0 + t + k * 256;
    bool valid = e < N_EDGES_C;
    rr[k] = valid ? row[e] : -1;
    cc[k] = valid ? col[e] : 0;
    vv[k] = valid ? vals[e] : 0.f;
  }
#pragma unroll
  for (int k = 0; k < EPT; ++k) {
    bn[k] = (rr[k] >= 0) ? (rr[k] >> 10) : -1;
    if (bn[k] >= 0) atomicAdd(&hist[bn[k]], 1);
  }
  __syncthreads();
  if (t < 128) scanarr[t] = hist[t];
  __syncthreads();
#pragma unroll
  for (int off = 1; off < 128; off <<= 1) {
    int u = 0;
    if (t < 128 && t >= off) u = scanarr[t - off];
    __syncthreads();
    if (t < 128) scanarr[t] += u;
    __syncthreads();
  }
  // scanarr = inclusive prefix; chunk-local start of bin b = scanarr[b]-hist[b]
  if (t < BINS && hist[t] > 0) basearr[t] = atomicAdd(&bincur[t], hist[t]);
#pragma unroll
  for (int k = 0; k < EPT; ++k) {
    if (bn[k] >= 0) {
      int lstart = scanarr[bn[k]] - hist[bn[k]];
      int slot = lstart + atomicAdd(&cnt2[bn[k]], 1);
      s_cv[slot] = make_int2(cc[k], __float_as_int(vv[k]));
      s_r[slot] = rr[k];
      s_bin[slot] = (unsigned char)bn[k];
    }
  }
  __syncthreads();
  int totv = scanarr[127];
  for (int s = t; s < totv; s += 256) {
    int b = s_bin[s];
    int lstart = scanarr[b] - hist[b];
    int g = basearr[b] + (s - lstart);
    stage_cv[g] = s_cv[s];
    stage_r[g] = s_r[s];
  }
}

// ---------------- Pass B: parity-interleaved scatter-from-stage / LN+GEMM1 ---
// even blocks: grid-tiled scatter of the bin-ordered stage (sequential reads,
// destination confined to ~130KB window per run). odd blocks: LN+GEMM1.
// Parity interleave keeps both roles co-resident from t=0 (r9/r16 lesson).
__global__ __launch_bounds__(256) void binscatter_ln_kernel(
    const int2* __restrict__ stage_cv, const int* __restrict__ stage_r,
    int* __restrict__ cursor, int2* __restrict__ edges_s,
    const float* __restrict__ x, const float* __restrict__ gamma,
    const float* __restrict__ beta, const float* __restrict__ W1,
    const float* __restrict__ b1, ushort_t* __restrict__ y) {
  if ((blockIdx.x & 1) == 0) {
    int i0 = (blockIdx.x >> 1) * 2048;
    if (i0 >= N_EDGES_C) return;
    int t = threadIdx.x;
    int2 cv[8];
    int rn[8], p[8];
    bool in[8];
#pragma unroll
    for (int k = 0; k < 8; ++k) {
      int i = i0 + t + k * 256;
      in[k] = i < N_EDGES_C;
      cv[k] = in[k] ? stage_cv[i] : make_int2(0, 0);
      rn[k] = in[k] ? stage_r[i] : 0;
    }
#pragma unroll
    for (int k = 0; k < 8; ++k)
      if (in[k]) p[k] = atomicAdd(&cursor[rn[k]], 1);
#pragma unroll
    for (int k = 0; k < 8; ++k)
      if (in[k]) edges_s[p[k]] = cv[k];
  } else {
    int lane = threadIdx.x & 63;
    int wid = (blockIdx.x >> 1) * 4 + (threadIdx.x >> 6);
    const int nw = LN_BLOCKS * 4;
    float bias = b1[lane];
    float g0 = gamma[lane];
    float be0 = beta[lane];
    float g1 = (lane < 36) ? gamma[64 + lane] : 0.f;
    float be1 = (lane < 36) ? beta[64 + lane] : 0.f;
    for (int n = wid; n < N_NODES_C; n += nw) {
      const float* xr = x + (size_t)n * 100;
      float x0 = xr[lane];
      float x1 = (lane < 36) ? xr[64 + lane] : 0.f;
      x0 = fminf(fmaxf(x0, -CLAMP_C), CLAMP_C);
      x1 = fminf(fmaxf(x1, -CLAMP_C), CLAMP_C);
      float mu = wave_sum(x0 + x1) * 0.01f;
      float d0 = x0 - mu;
      float d1 = (lane < 36) ? (x1 - mu) : 0.f;
      float var = wave_sum(d0 * d0 + d1 * d1) * 0.01f;
      float inv = rsqrtf(var + LN_EPS_C);
      float xn0 = d0 * inv * g0 + be0;
      float xn1 = d1 * inv * g1 + be1;
      float acc = bias;
#pragma unroll
      for (int k = 0; k < 64; ++k) acc = fmaf(readlane_f(xn0, k), W1[k * 64 + lane], acc);
#pragma unroll
      for (int k = 0; k < 36; ++k) acc = fmaf(readlane_f(xn1, k), W1[(64 + k) * 64 + lane], acc);
      y[(size_t)n * 64 + lane] = f2bf(acc);
    }
  }
}

// ---------------- SpMM (bf16 gather, 16-way ILP) + ELU + GEMM(64->DOUT) ------
// Round-13 known-good structure: VGPR ~64, occupancy ~43%. Both more VGPRs
// (dual-row, r12: 282us) and fewer (forced 32 -> scratch spill, r15: 520us)
// are large regressions.
template <int DOUT>
__global__ __launch_bounds__(256) void spmm_elu_gemm_kernel(
    const int* __restrict__ rowstart, const int* __restrict__ counts,
    const int2* __restrict__ edges_s, const ushort_t* __restrict__ yb,
    const float* __restrict__ W, const float* __restrict__ b,
    ushort_t* __restrict__ out) {
  int lane = threadIdx.x & 63;
  int wid = blockIdx.x * (blockDim.x >> 6) + (threadIdx.x >> 6);
  int nw = gridDim.x * (blockDim.x >> 6);
  float w[64];
#pragma unroll
  for (int k = 0; k < 64; ++k) w[k] = (lane < DOUT) ? W[k * DOUT + lane] : 0.f;
  float bias = (lane < DOUT) ? b[lane] : 0.f;
  for (int n = wid; n < N_NODES_C; n += nw) {
    int start = rowstart[n];
    int cnt = counts[n];
    float a[8];
#pragma unroll
    for (int u = 0; u < 8; ++u) a[u] = 0.f;
    for (int base = 0; base < cnt; base += 64) {
      int m = cnt - base;
      if (m > 64) m = 64;
      int2 ev = make_int2(0, 0);
      if (lane < m) ev = edges_s[start + base + lane];
      int mr = (m + 15) & ~15;
      for (int j = 0; j < mr; j += 16) {
        float g[16];
#pragma unroll
        for (int u = 0; u < 16; ++u)
          g[u] = bf2f(yb[(size_t)__builtin_amdgcn_readlane(ev.x, j + u) * 64 + lane]);
#pragma unroll
        for (int u = 0; u < 16; ++u)
          a[u & 7] = fmaf(
              __uint_as_float(__builtin_amdgcn_readlane((unsigned)ev.y, j + u)), g[u],
              a[u & 7]);
      }
    }
    float acc = ((a[0] + a[1]) + (a[2] + a[3])) + ((a[4] + a[5]) + (a[6] + a[7]));
    // ELU
    float xe = (acc > 0.f) ? acc : expm1f(acc);
    // GEMM: out[n][lane] = bias + sum_k xe_k * W[k][lane]
    float o = bias;
#pragma unroll
    for (int k = 0; k < 64; ++k) o = fmaf(readlane_f(xe, k), w[k], o);
    if (lane < DOUT) out[(size_t)n * 64 + lane] = f2bf(o);
  }
}

// ---------------- final SpMM (bf16 gather, 16-way ILP, 47 valid) -> fp32 -----
__global__ __launch_bounds__(256) void spmm_final_kernel(
    const int* __restrict__ rowstart, const int* __restrict__ counts,
    const int2* __restrict__ edges_s, const ushort_t* __restrict__ yb,
    float* __restrict__ out) {
  int lane = threadIdx.x & 63;
  int wid = blockIdx.x * (blockDim.x >> 6) + (threadIdx.x >> 6);
  int nw = gridDim.x * (blockDim.x >> 6);
  int lmask = (lane < 47) ? lane : 46;  // OOB lanes stay inside the row; unused
  for (int n = wid; n < N_NODES_C; n += nw) {
    int start = rowstart[n];
    int cnt = counts[n];
    float a[8];
#pragma unroll
    for (int u = 0; u < 8; ++u) a[u] = 0.f;
    for (int base = 0; base < cnt; base += 64) {
      int m = cnt - base;
      if (m > 64) m = 64;
      int2 ev = make_int2(0, 0);
      if (lane < m) ev = edges_s[start + base + lane];
      int mr = (m + 15) & ~15;
      for (int j = 0; j < mr; j += 16) {
        float g[16];
#pragma unroll
        for (int u = 0; u < 16; ++u)
          g[u] = bf2f(yb[(size_t)__builtin_amdgcn_readlane(ev.x, j + u) * 64 + lmask]);
#pragma unroll
        for (int u = 0; u < 16; ++u)
          a[u & 7] = fmaf(
              __uint_as_float(__builtin_amdgcn_readlane((unsigned)ev.y, j + u)), g[u],
              a[u & 7]);
      }
    }
    float acc = ((a[0] + a[1]) + (a[2] + a[3])) + ((a[4] + a[5]) + (a[6] + a[7]));
    if (lane < 47) out[(size_t)n * 47 + lane] = acc;
  }
}

extern "C" void kernel_launch(void* const* d_in, const int* in_sizes, int n_in,
                              void* d_out, int out_size, void* d_ws, size_t ws_size,
                              hipStream_t stream) {
  const float* x = (const float*)d_in[0];
  const float* adj_vals = (const float*)d_in[1];
  const int* adj_row = (const int*)d_in[2];
  const int* adj_col = (const int*)d_in[3];
  const float* gamma = (const float*)d_in[4];
  const float* beta = (const float*)d_in[5];
  const float* W1 = (const float*)d_in[6];
  const float* b1 = (const float*)d_in[7];
  const float* W2 = (const float*)d_in[8];
  const float* b2 = (const float*)d_in[9];
  const float* W3 = (const float*)d_in[10];
  const float* b3 = (const float*)d_in[11];
  float* out = (float*)d_out;

  char* ws = (char*)d_ws;
  size_t off = 0;
  auto alloc = [&](size_t bytes) -> void* {
    void* p = ws + off;
    off += (bytes + 255) & ~(size_t)255;
    return p;
  };
  ushort_t* bufA = (ushort_t*)alloc(sizeof(ushort_t) * (size_t)N_NODES_C * 64);
  ushort_t* bufB = (ushort_t*)alloc(sizeof(ushort_t) * (size_t)N_NODES_C * 64);
  int* counts = (int*)alloc(sizeof(int) * N_NODES_C);
  int* cursor = (int*)alloc(sizeof(int) * N_NODES_C);
  int* rowstart = (int*)alloc(sizeof(int) * N_NODES_C);
  int* bsums = (int*)alloc(sizeof(int) * 256);
  int* bincur = (int*)alloc(sizeof(int) * 128);
  int2* edges_s = (int2*)alloc(sizeof(int2) * N_EDGES_C);
  int2* stage_cv = (int2*)alloc(sizeof(int2) * N_EDGES_C);
  int* stage_r = (int*)alloc(sizeof(int) * N_EDGES_C);

  hipMemsetAsync(counts, 0, sizeof(int) * N_NODES_C, stream);

  // 1.6M edges / (256 th * 8) = 782 blocks
  hist_kernel<<<782, 256, 0, stream>>>(adj_row, counts);
  int nb = (N_NODES_C + 1023) / 1024;  // 98
  scan1_kernel<<<nb, 256, 0, stream>>>(counts, rowstart, bsums);
  scan2_kernel<<<1, 128, 0, stream>>>(bsums, nb);
  scan3_kernel<<<nb, 256, 0, stream>>>(rowstart, cursor, bincur, bsums);

  // Pass A: radix-partition edges into bin-ordered staging (sequential runs)
  partition_kernel<<<NCHUNK, 256, 0, stream>>>(adj_row, adj_col, adj_vals, bincur,
                                               stage_cv, stage_r);
  // Pass B: even blocks scatter the stage (all CUs), odd blocks LN+GEMM1
  binscatter_ln_kernel<<<2048, 256, 0, stream>>>(
      stage_cv, stage_r, cursor, edges_s, x, gamma, beta, W1, b1, bufA);

  // h2 = ELU(spmm(h1)) @ W2 + b2   (bf16 in/out, pitch 64)
  spmm_elu_gemm_kernel<64><<<2048, 256, 0, stream>>>(rowstart, counts, edges_s, bufA,
                                                     W2, b2, bufB);
  // h3 = ELU(spmm(h2)) @ W3 + b3   (bf16 in/out, pitch 64, 47 valid)
  spmm_elu_gemm_kernel<47><<<2048, 256, 0, stream>>>(rowstart, counts, edges_s, bufB,
                                                     W3, b3, bufA);
  // out = spmm(h3)  (fp32 out)
  spmm_final_kernel<<<2048, 256, 0, stream>>>(rowstart, counts, edges_s, bufA, out);
}

// Round 20
// 412.128 us; speedup vs baseline: 1.0258x; 1.0258x over previous
//
#include <hip/hip_runtime.h>
#include <cstdint>
#include <cstddef>

#define N_NODES_C 100000
#define N_EDGES_C 1600000
#define LN_EPS_C 1e-5f
#define CLAMP_C 1.8f
#define LN_BLOCKS 1024
// Radix-binned scatter: bin = row >> 8 (256 rows/bin), 391 bins.
// Staging layout is CSR-aligned (bincur init = rowstart at bin boundaries).
// r18->r20: finer bins = 4x exclusive single-writer scatter blocks (r19 showed
// exclusivity is what matters, not write coalescing).
#define BINS 391
#define BIN_SHIFT 8
#define CHUNK 4096
#define EPT 16
#define NCHUNK 391  // ceil(1.6M / 4096)

typedef unsigned short ushort_t;

__device__ __forceinline__ float readlane_f(float v, int l) {
  return __uint_as_float(__builtin_amdgcn_readlane(__float_as_uint(v), l));
}

__device__ __forceinline__ float wave_sum(float v) {
#pragma unroll
  for (int off = 32; off > 0; off >>= 1) v += __shfl_xor(v, off, 64);
  return v;
}

// bf16 pack (round-to-nearest-even) / unpack
__device__ __forceinline__ ushort_t f2bf(float f) {
  unsigned u = __float_as_uint(f);
  unsigned r = (u + 0x7fffu + ((u >> 16) & 1u)) >> 16;
  return (ushort_t)r;
}
__device__ __forceinline__ float bf2f(ushort_t u) {
  return __uint_as_float((unsigned)u << 16);
}

// ---------------- CSR build ----------------
__global__ __launch_bounds__(256) void hist_kernel(const int* __restrict__ row,
                                                   int* __restrict__ counts) {
  int tid = blockIdx.x * blockDim.x + threadIdx.x;
  int nt = gridDim.x * blockDim.x;
  int r[8];
#pragma unroll
  for (int k = 0; k < 8; ++k) {
    int e = tid + k * nt;
    r[k] = (e < N_EDGES_C) ? row[e] : -1;
  }
#pragma unroll
  for (int k = 0; k < 8; ++k)
    if (r[k] >= 0) atomicAdd(&counts[r[k]], 1);
}

__global__ void scan1_kernel(const int* __restrict__ counts, int* __restrict__ rowstart,
                             int* __restrict__ bsums) {
  __shared__ int lds[256];
  int t = threadIdx.x;
  int base = blockIdx.x * 1024 + t * 4;
  int c0 = (base + 0 < N_NODES_C) ? counts[base + 0] : 0;
  int c1 = (base + 1 < N_NODES_C) ? counts[base + 1] : 0;
  int c2 = (base + 2 < N_NODES_C) ? counts[base + 2] : 0;
  int c3 = (base + 3 < N_NODES_C) ? counts[base + 3] : 0;
  int s = c0 + c1 + c2 + c3;
  lds[t] = s;
  __syncthreads();
#pragma unroll
  for (int off = 1; off < 256; off <<= 1) {
    int v = (t >= off) ? lds[t - off] : 0;
    __syncthreads();
    lds[t] += v;
    __syncthreads();
  }
  int incl = lds[t];
  int excl = incl - s;
  if (t == 255) bsums[blockIdx.x] = incl;
  if (base + 0 < N_NODES_C) rowstart[base + 0] = excl;
  excl += c0;
  if (base + 1 < N_NODES_C) rowstart[base + 1] = excl;
  excl += c1;
  if (base + 2 < N_NODES_C) rowstart[base + 2] = excl;
  excl += c2;
  if (base + 3 < N_NODES_C) rowstart[base + 3] = excl;
}

__global__ void scan2_kernel(int* __restrict__ bsums, int nb) {
  __shared__ int lds[128];
  int t = threadIdx.x;
  int v = (t < nb) ? bsums[t] : 0;
  lds[t] = v;
  __syncthreads();
#pragma unroll
  for (int off = 1; off < 128; off <<= 1) {
    int u = (t >= off) ? lds[t - off] : 0;
    __syncthreads();
    lds[t] += u;
    __syncthreads();
  }
  if (t < nb) bsums[t] = lds[t] - v;
}

// final rowstart + cursor copy + per-bin staging cursors (CSR-aligned)
__global__ void scan3_kernel(int* __restrict__ rowstart, int* __restrict__ cursor,
                             int* __restrict__ bincur, const int* __restrict__ bsums) {
  int add = bsums[blockIdx.x];
  int base = blockIdx.x * 1024 + threadIdx.x * 4;
#pragma unroll
  for (int i = 0; i < 4; ++i) {
    int rI = base + i;
    if (rI < N_NODES_C) {
      int v = rowstart[rI] + add;
      rowstart[rI] = v;
      cursor[rI] = v;
      if ((rI & 255) == 0) bincur[rI >> BIN_SHIFT] = v;
    }
  }
}

// ---------------- Pass A: block-local radix partition into bin-ordered staging
// Each block: 4096-edge chunk -> LDS hist(391) -> scan -> LDS reorder -> one
// global range reservation per bin -> sequential copy-out runs per bin.
// Staging is CSR-aligned; stage_r carries the full row id.
__global__ __launch_bounds__(256) void partition_kernel(
    const int* __restrict__ row, const int* __restrict__ col,
    const float* __restrict__ vals, int* __restrict__ bincur,
    int2* __restrict__ stage_cv, int* __restrict__ stage_r) {
  __shared__ int hist[512];
  __shared__ int scanarr[512];
  __shared__ int cnt2[512];
  __shared__ int basearr[512];
  __shared__ int2 s_cv[CHUNK];
  __shared__ int s_r[CHUNK];
  int t = threadIdx.x;
  int e0 = blockIdx.x * CHUNK;
  for (int b = t; b < 512; b += 256) {
    hist[b] = 0;
    cnt2[b] = 0;
    basearr[b] = 0;
  }
  __syncthreads();
  int rr[EPT], cc[EPT], bn[EPT];
  float vv[EPT];
#pragma unroll
  for (int k = 0; k < EPT; ++k) {
    int e = e0 + t + k * 256;
    bool valid = e < N_EDGES_C;
    rr[k] = valid ? row[e] : -1;
    cc[k] = valid ? col[e] : 0;
    vv[k] = valid ? vals[e] : 0.f;
  }
#pragma unroll
  for (int k = 0; k < EPT; ++k) {
    bn[k] = (rr[k] >= 0) ? (rr[k] >> BIN_SHIFT) : -1;
    if (bn[k] >= 0) atomicAdd(&hist[bn[k]], 1);
  }
  __syncthreads();
  // inclusive scan over 512 entries, two halves of 256 with 256 threads
  scanarr[t] = hist[t];
  __syncthreads();
#pragma unroll
  for (int off = 1; off < 256; off <<= 1) {
    int u = (t >= off) ? scanarr[t - off] : 0;
    __syncthreads();
    scanarr[t] += u;
    __syncthreads();
  }
  scanarr[256 + t] = hist[256 + t];
  __syncthreads();
#pragma unroll
  for (int off = 1; off < 256; off <<= 1) {
    int u = (t >= off) ? scanarr[256 + t - off] : 0;
    __syncthreads();
    scanarr[256 + t] += u;
    __syncthreads();
  }
  int tot0 = scanarr[255];
  __syncthreads();
  scanarr[256 + t] += tot0;
  __syncthreads();
  // global range reservation (one atomic per non-empty bin)
  for (int b = t; b < BINS; b += 256)
    if (hist[b] > 0) basearr[b] = atomicAdd(&bincur[b], hist[b]);
  // LDS reorder into bin-grouped layout
#pragma unroll
  for (int k = 0; k < EPT; ++k) {
    if (bn[k] >= 0) {
      int lstart = scanarr[bn[k]] - hist[bn[k]];
      int slot = lstart + atomicAdd(&cnt2[bn[k]], 1);
      s_cv[slot] = make_int2(cc[k], __float_as_int(vv[k]));
      s_r[slot] = rr[k];
    }
  }
  __syncthreads();
  int totv = scanarr[511];
  for (int s = t; s < totv; s += 256) {
    int b = s_r[s] >> BIN_SHIFT;
    int lstart = scanarr[b] - hist[b];
    int g = basearr[b] + (s - lstart);
    stage_cv[g] = s_cv[s];
    stage_r[g] = s_r[s];
  }
}

// ---------------- Pass B (blocks [0,391)): bin-exclusive scatter; blocks
// [391,391+LN_BLOCKS): LN+GEMM1. Each scatter block reads its bin's staging
// sequentially and scatters into its exclusive 32KB CSR dest window (single
// writer); cursor atomics are bin-exclusive.
__global__ __launch_bounds__(256) void binscatter_ln_kernel(
    const int* __restrict__ rowstart, const int2* __restrict__ stage_cv,
    const int* __restrict__ stage_r, int* __restrict__ cursor,
    int2* __restrict__ edges_s,
    const float* __restrict__ x, const float* __restrict__ gamma,
    const float* __restrict__ beta, const float* __restrict__ W1,
    const float* __restrict__ b1, ushort_t* __restrict__ y) {
  if (blockIdx.x < BINS) {
    int b = blockIdx.x;
    int t = threadIdx.x;
    int lo = rowstart[b << BIN_SHIFT];
    int hi = (b == BINS - 1) ? N_EDGES_C : rowstart[(b + 1) << BIN_SHIFT];
    for (int i0 = lo; i0 < hi; i0 += 2048) {
      int2 cv[8];
      int rn[8], p[8];
      bool in[8];
#pragma unroll
      for (int k = 0; k < 8; ++k) {
        int i = i0 + t + k * 256;
        in[k] = i < hi;
        cv[k] = in[k] ? stage_cv[i] : make_int2(0, 0);
        rn[k] = in[k] ? stage_r[i] : 0;
      }
#pragma unroll
      for (int k = 0; k < 8; ++k)
        if (in[k]) p[k] = atomicAdd(&cursor[rn[k]], 1);
#pragma unroll
      for (int k = 0; k < 8; ++k)
        if (in[k]) edges_s[p[k]] = cv[k];
    }
  } else {
    int lane = threadIdx.x & 63;
    int wid = ((int)blockIdx.x - BINS) * 4 + (threadIdx.x >> 6);
    const int nw = LN_BLOCKS * 4;
    float bias = b1[lane];
    float g0 = gamma[lane];
    float be0 = beta[lane];
    float g1 = (lane < 36) ? gamma[64 + lane] : 0.f;
    float be1 = (lane < 36) ? beta[64 + lane] : 0.f;
    for (int n = wid; n < N_NODES_C; n += nw) {
      const float* xr = x + (size_t)n * 100;
      float x0 = xr[lane];
      float x1 = (lane < 36) ? xr[64 + lane] : 0.f;
      x0 = fminf(fmaxf(x0, -CLAMP_C), CLAMP_C);
      x1 = fminf(fmaxf(x1, -CLAMP_C), CLAMP_C);
      float mu = wave_sum(x0 + x1) * 0.01f;
      float d0 = x0 - mu;
      float d1 = (lane < 36) ? (x1 - mu) : 0.f;
      float var = wave_sum(d0 * d0 + d1 * d1) * 0.01f;
      float inv = rsqrtf(var + LN_EPS_C);
      float xn0 = d0 * inv * g0 + be0;
      float xn1 = d1 * inv * g1 + be1;
      float acc = bias;
#pragma unroll
      for (int k = 0; k < 64; ++k) acc = fmaf(readlane_f(xn0, k), W1[k * 64 + lane], acc);
#pragma unroll
      for (int k = 0; k < 36; ++k) acc = fmaf(readlane_f(xn1, k), W1[(64 + k) * 64 + lane], acc);
      y[(size_t)n * 64 + lane] = f2bf(acc);
    }
  }
}

// ---------------- SpMM (bf16 gather, 16-way ILP) + ELU + GEMM(64->DOUT) ------
// Round-13 known-good structure: VGPR ~64, occupancy ~43%. Both more VGPRs
// (dual-row, r12: 282us) and fewer (forced 32 -> scratch spill, r15: 520us)
// are large regressions.
template <int DOUT>
__global__ __launch_bounds__(256) void spmm_elu_gemm_kernel(
    const int* __restrict__ rowstart, const int* __restrict__ counts,
    const int2* __restrict__ edges_s, const ushort_t* __restrict__ yb,
    const float* __restrict__ W, const float* __restrict__ b,
    ushort_t* __restrict__ out) {
  int lane = threadIdx.x & 63;
  int wid = blockIdx.x * (blockDim.x >> 6) + (threadIdx.x >> 6);
  int nw = gridDim.x * (blockDim.x >> 6);
  float w[64];
#pragma unroll
  for (int k = 0; k < 64; ++k) w[k] = (lane < DOUT) ? W[k * DOUT + lane] : 0.f;
  float bias = (lane < DOUT) ? b[lane] : 0.f;
  for (int n = wid; n < N_NODES_C; n += nw) {
    int start = rowstart[n];
    int cnt = counts[n];
    float a[8];
#pragma unroll
    for (int u = 0; u < 8; ++u) a[u] = 0.f;
    for (int base = 0; base < cnt; base += 64) {
      int m = cnt - base;
      if (m > 64) m = 64;
      int2 ev = make_int2(0, 0);
      if (lane < m) ev = edges_s[start + base + lane];
      int mr = (m + 15) & ~15;
      for (int j = 0; j < mr; j += 16) {
        float g[16];
#pragma unroll
        for (int u = 0; u < 16; ++u)
          g[u] = bf2f(yb[(size_t)__builtin_amdgcn_readlane(ev.x, j + u) * 64 + lane]);
#pragma unroll
        for (int u = 0; u < 16; ++u)
          a[u & 7] = fmaf(
              __uint_as_float(__builtin_amdgcn_readlane((unsigned)ev.y, j + u)), g[u],
              a[u & 7]);
      }
    }
    float acc = ((a[0] + a[1]) + (a[2] + a[3])) + ((a[4] + a[5]) + (a[6] + a[7]));
    // ELU
    float xe = (acc > 0.f) ? acc : expm1f(acc);
    // GEMM: out[n][lane] = bias + sum_k xe_k * W[k][lane]
    float o = bias;
#pragma unroll
    for (int k = 0; k < 64; ++k) o = fmaf(readlane_f(xe, k), w[k], o);
    if (lane < DOUT) out[(size_t)n * 64 + lane] = f2bf(o);
  }
}

// ---------------- final SpMM (bf16 gather, 16-way ILP, 47 valid) -> fp32 -----
__global__ __launch_bounds__(256) void spmm_final_kernel(
    const int* __restrict__ rowstart, const int* __restrict__ counts,
    const int2* __restrict__ edges_s, const ushort_t* __restrict__ yb,
    float* __restrict__ out) {
  int lane = threadIdx.x & 63;
  int wid = blockIdx.x * (blockDim.x >> 6) + (threadIdx.x >> 6);
  int nw = gridDim.x * (blockDim.x >> 6);
  int lmask = (lane < 47) ? lane : 46;  // OOB lanes stay inside the row; unused
  for (int n = wid; n < N_NODES_C; n += nw) {
    int start = rowstart[n];
    int cnt = counts[n];
    float a[8];
#pragma unroll
    for (int u = 0; u < 8; ++u) a[u] = 0.f;
    for (int base = 0; base < cnt; base += 64) {
      int m = cnt - base;
      if (m > 64) m = 64;
      int2 ev = make_int2(0, 0);
      if (lane < m) ev = edges_s[start + base + lane];
      int mr = (m + 15) & ~15;
      for (int j = 0; j < mr; j += 16) {
        float g[16];
#pragma unroll
        for (int u = 0; u < 16; ++u)
          g[u] = bf2f(yb[(size_t)__builtin_amdgcn_readlane(ev.x, j + u) * 64 + lmask]);
#pragma unroll
        for (int u = 0; u < 16; ++u)
          a[u & 7] = fmaf(
              __uint_as_float(__builtin_amdgcn_readlane((unsigned)ev.y, j + u)), g[u],
              a[u & 7]);
      }
    }
    float acc = ((a[0] + a[1]) + (a[2] + a[3])) + ((a[4] + a[5]) + (a[6] + a[7]));
    if (lane < 47) out[(size_t)n * 47 + lane] = acc;
  }
}

extern "C" void kernel_launch(void* const* d_in, const int* in_sizes, int n_in,
                              void* d_out, int out_size, void* d_ws, size_t ws_size,
                              hipStream_t stream) {
  const float* x = (const float*)d_in[0];
  const float* adj_vals = (const float*)d_in[1];
  const int* adj_row = (const int*)d_in[2];
  const int* adj_col = (const int*)d_in[3];
  const float* gamma = (const float*)d_in[4];
  const float* beta = (const float*)d_in[5];
  const float* W1 = (const float*)d_in[6];
  const float* b1 = (const float*)d_in[7];
  const float* W2 = (const float*)d_in[8];
  const float* b2 = (const float*)d_in[9];
  const float* W3 = (const float*)d_in[10];
  const float* b3 = (const float*)d_in[11];
  float* out = (float*)d_out;

  char* ws = (char*)d_ws;
  size_t off = 0;
  auto alloc = [&](size_t bytes) -> void* {
    void* p = ws + off;
    off += (bytes + 255) & ~(size_t)255;
    return p;
  };
  ushort_t* bufA = (ushort_t*)alloc(sizeof(ushort_t) * (size_t)N_NODES_C * 64);
  ushort_t* bufB = (ushort_t*)alloc(sizeof(ushort_t) * (size_t)N_NODES_C * 64);
  int* counts = (int*)alloc(sizeof(int) * N_NODES_C);
  int* cursor = (int*)alloc(sizeof(int) * N_NODES_C);
  int* rowstart = (int*)alloc(sizeof(int) * N_NODES_C);
  int* bsums = (int*)alloc(sizeof(int) * 256);
  int* bincur = (int*)alloc(sizeof(int) * 512);
  int2* edges_s = (int2*)alloc(sizeof(int2) * N_EDGES_C);
  int2* stage_cv = (int2*)alloc(sizeof(int2) * N_EDGES_C);
  int* stage_r = (int*)alloc(sizeof(int) * N_EDGES_C);

  hipMemsetAsync(counts, 0, sizeof(int) * N_NODES_C, stream);

  // 1.6M edges / (256 th * 8) = 782 blocks
  hist_kernel<<<782, 256, 0, stream>>>(adj_row, counts);
  int nb = (N_NODES_C + 1023) / 1024;  // 98
  scan1_kernel<<<nb, 256, 0, stream>>>(counts, rowstart, bsums);
  scan2_kernel<<<1, 128, 0, stream>>>(bsums, nb);
  scan3_kernel<<<nb, 256, 0, stream>>>(rowstart, cursor, bincur, bsums);

  // Pass A: radix-partition edges into bin-ordered staging (sequential runs)
  partition_kernel<<<NCHUNK, 256, 0, stream>>>(adj_row, adj_col, adj_vals, bincur,
                                               stage_cv, stage_r);
  // Pass B (391 bin-exclusive scatter blocks) + LN+GEMM1 (1024 blocks)
  binscatter_ln_kernel<<<BINS + LN_BLOCKS, 256, 0, stream>>>(
      rowstart, stage_cv, stage_r, cursor, edges_s, x, gamma, beta, W1, b1, bufA);

  // h2 = ELU(spmm(h1)) @ W2 + b2   (bf16 in/out, pitch 64)
  spmm_elu_gemm_kernel<64><<<2048, 256, 0, stream>>>(rowstart, counts, edges_s, bufA,
                                                     W2, b2, bufB);
  // h3 = ELU(spmm(h2)) @ W3 + b3   (bf16 in/out, pitch 64, 47 valid)
  spmm_elu_gemm_kernel<47><<<2048, 256, 0, stream>>>(rowstart, counts, edges_s, bufB,
                                                     W3, b3, bufA);
  // out = spmm(h3)  (fp32 out)
  spmm_final_kernel<<<2048, 256, 0, stream>>>(rowstart, counts, edges_s, bufA, out);
}

// Round 21
// 394.086 us; speedup vs baseline: 1.0727x; 1.0458x over previous
//
#include <hip/hip_runtime.h>
#include <cstdint>
#include <cstddef>

#define N_NODES_C 100000
#define N_EDGES_C 1600000
#define LN_EPS_C 1e-5f
#define CLAMP_C 1.8f
#define LN_BLOCKS 1024
// Radix-binned scatter: bin = row >> 10 (1024 rows/bin), 98 bins.
// Staging layout is CSR-aligned (bincur init = rowstart at bin boundaries).
// r18 configuration == session best (395us). r19 (shared writers) and r20
// (391 finer bins) both measured worse/neutral; 98 bin-exclusive writers is
// the validated optimum for pass B.
#define BINS 98
#define CHUNK 4096
#define EPT 16
#define NCHUNK 391  // ceil(1.6M / 4096)

typedef unsigned short ushort_t;

__device__ __forceinline__ float readlane_f(float v, int l) {
  return __uint_as_float(__builtin_amdgcn_readlane(__float_as_uint(v), l));
}

__device__ __forceinline__ float wave_sum(float v) {
#pragma unroll
  for (int off = 32; off > 0; off >>= 1) v += __shfl_xor(v, off, 64);
  return v;
}

// bf16 pack (round-to-nearest-even) / unpack
__device__ __forceinline__ ushort_t f2bf(float f) {
  unsigned u = __float_as_uint(f);
  unsigned r = (u + 0x7fffu + ((u >> 16) & 1u)) >> 16;
  return (ushort_t)r;
}
__device__ __forceinline__ float bf2f(ushort_t u) {
  return __uint_as_float((unsigned)u << 16);
}

// ---------------- CSR build ----------------
__global__ __launch_bounds__(256) void hist_kernel(const int* __restrict__ row,
                                                   int* __restrict__ counts) {
  int tid = blockIdx.x * blockDim.x + threadIdx.x;
  int nt = gridDim.x * blockDim.x;
  int r[8];
#pragma unroll
  for (int k = 0; k < 8; ++k) {
    int e = tid + k * nt;
    r[k] = (e < N_EDGES_C) ? row[e] : -1;
  }
#pragma unroll
  for (int k = 0; k < 8; ++k)
    if (r[k] >= 0) atomicAdd(&counts[r[k]], 1);
}

__global__ void scan1_kernel(const int* __restrict__ counts, int* __restrict__ rowstart,
                             int* __restrict__ bsums) {
  __shared__ int lds[256];
  int t = threadIdx.x;
  int base = blockIdx.x * 1024 + t * 4;
  int c0 = (base + 0 < N_NODES_C) ? counts[base + 0] : 0;
  int c1 = (base + 1 < N_NODES_C) ? counts[base + 1] : 0;
  int c2 = (base + 2 < N_NODES_C) ? counts[base + 2] : 0;
  int c3 = (base + 3 < N_NODES_C) ? counts[base + 3] : 0;
  int s = c0 + c1 + c2 + c3;
  lds[t] = s;
  __syncthreads();
#pragma unroll
  for (int off = 1; off < 256; off <<= 1) {
    int v = (t >= off) ? lds[t - off] : 0;
    __syncthreads();
    lds[t] += v;
    __syncthreads();
  }
  int incl = lds[t];
  int excl = incl - s;
  if (t == 255) bsums[blockIdx.x] = incl;
  if (base + 0 < N_NODES_C) rowstart[base + 0] = excl;
  excl += c0;
  if (base + 1 < N_NODES_C) rowstart[base + 1] = excl;
  excl += c1;
  if (base + 2 < N_NODES_C) rowstart[base + 2] = excl;
  excl += c2;
  if (base + 3 < N_NODES_C) rowstart[base + 3] = excl;
}

__global__ void scan2_kernel(int* __restrict__ bsums, int nb) {
  __shared__ int lds[128];
  int t = threadIdx.x;
  int v = (t < nb) ? bsums[t] : 0;
  lds[t] = v;
  __syncthreads();
#pragma unroll
  for (int off = 1; off < 128; off <<= 1) {
    int u = (t >= off) ? lds[t - off] : 0;
    __syncthreads();
    lds[t] += u;
    __syncthreads();
  }
  if (t < nb) bsums[t] = lds[t] - v;
}

// final rowstart + cursor copy + per-bin staging cursors (CSR-aligned)
__global__ void scan3_kernel(int* __restrict__ rowstart, int* __restrict__ cursor,
                             int* __restrict__ bincur, const int* __restrict__ bsums) {
  int add = bsums[blockIdx.x];
  int base = blockIdx.x * 1024 + threadIdx.x * 4;
#pragma unroll
  for (int i = 0; i < 4; ++i) {
    int rI = base + i;
    if (rI < N_NODES_C) {
      int v = rowstart[rI] + add;
      rowstart[rI] = v;
      cursor[rI] = v;
      if ((rI & 1023) == 0) bincur[rI >> 10] = v;
    }
  }
}

// ---------------- Pass A: block-local radix partition into bin-ordered staging
// Each block: 4096-edge chunk -> LDS hist(98) -> scan -> LDS reorder -> one
// global range reservation per bin -> copy-out as ~42-record sequential runs
// per bin (full-line stores). Staging is CSR-aligned.
__global__ __launch_bounds__(256) void partition_kernel(
    const int* __restrict__ row, const int* __restrict__ col,
    const float* __restrict__ vals, int* __restrict__ bincur,
    int2* __restrict__ stage_cv, ushort_t* __restrict__ stage_rlo) {
  __shared__ int hist[128];
  __shared__ int scanarr[128];
  __shared__ int cnt2[128];
  __shared__ int basearr[128];
  __shared__ int2 s_cv[CHUNK];
  __shared__ ushort_t s_rlo[CHUNK];
  __shared__ unsigned char s_bin[CHUNK];
  int t = threadIdx.x;
  int e0 = blockIdx.x * CHUNK;
  if (t < 128) {
    hist[t] = 0;
    cnt2[t] = 0;
    basearr[t] = 0;
  }
  __syncthreads();
  int rr[EPT], cc[EPT], bn[EPT];
  float vv[EPT];
#pragma unroll
  for (int k = 0; k < EPT; ++k) {
    int e = e0 + t + k * 256;
    bool valid = e < N_EDGES_C;
    rr[k] = valid ? row[e] : -1;
    cc[k] = valid ? col[e] : 0;
    vv[k] = valid ? vals[e] : 0.f;
  }
#pragma unroll
  for (int k = 0; k < EPT; ++k) {
    bn[k] = (rr[k] >= 0) ? (rr[k] >> 10) : -1;
    if (bn[k] >= 0) atomicAdd(&hist[bn[k]], 1);
  }
  __syncthreads();
  if (t < 128) scanarr[t] = hist[t];
  __syncthreads();
#pragma unroll
  for (int off = 1; off < 128; off <<= 1) {
    int u = 0;
    if (t < 128 && t >= off) u = scanarr[t - off];
    __syncthreads();
    if (t < 128) scanarr[t] += u;
    __syncthreads();
  }
  // scanarr = inclusive prefix; chunk-local start of bin b = scanarr[b]-hist[b]
  if (t < BINS && hist[t] > 0) basearr[t] = atomicAdd(&bincur[t], hist[t]);
#pragma unroll
  for (int k = 0; k < EPT; ++k) {
    if (bn[k] >= 0) {
      int lstart = scanarr[bn[k]] - hist[bn[k]];
      int slot = lstart + atomicAdd(&cnt2[bn[k]], 1);
      s_cv[slot] = make_int2(cc[k], __float_as_int(vv[k]));
      s_rlo[slot] = (ushort_t)(rr[k] & 1023);
      s_bin[slot] = (unsigned char)bn[k];
    }
  }
  __syncthreads();
  int totv = scanarr[127];
  for (int s = t; s < totv; s += 256) {
    int b = s_bin[s];
    int lstart = scanarr[b] - hist[b];
    int g = basearr[b] + (s - lstart);
    stage_cv[g] = s_cv[s];
    stage_rlo[g] = s_rlo[s];
  }
}

// ---------------- Pass B (blocks [0,98)): bin-exclusive scatter; blocks
// [98,98+LN_BLOCKS): LN+GEMM1. Pass B reads its bin's staging sequentially and
// scatters into its 128KB CSR dest window (single writer -> L2-resident);
// cursor atomics are bin-exclusive.
__global__ __launch_bounds__(256) void binscatter_ln_kernel(
    const int* __restrict__ rowstart, const int2* __restrict__ stage_cv,
    const ushort_t* __restrict__ stage_rlo, int* __restrict__ cursor,
    int2* __restrict__ edges_s,
    const float* __restrict__ x, const float* __restrict__ gamma,
    const float* __restrict__ beta, const float* __restrict__ W1,
    const float* __restrict__ b1, ushort_t* __restrict__ y) {
  if (blockIdx.x < BINS) {
    int b = blockIdx.x;
    int t = threadIdx.x;
    int lo = rowstart[b << 10];
    int hi = (b == BINS - 1) ? N_EDGES_C : rowstart[(b + 1) << 10];
    int rbase = b << 10;
    for (int i0 = lo; i0 < hi; i0 += 2048) {
      int2 cv[8];
      int rn[8], p[8];
      bool in[8];
#pragma unroll
      for (int k = 0; k < 8; ++k) {
        int i = i0 + t + k * 256;
        in[k] = i < hi;
        cv[k] = in[k] ? stage_cv[i] : make_int2(0, 0);
        rn[k] = in[k] ? (rbase | (int)stage_rlo[i]) : 0;
      }
#pragma unroll
      for (int k = 0; k < 8; ++k)
        if (in[k]) p[k] = atomicAdd(&cursor[rn[k]], 1);
#pragma unroll
      for (int k = 0; k < 8; ++k)
        if (in[k]) edges_s[p[k]] = cv[k];
    }
  } else {
    int lane = threadIdx.x & 63;
    int wid = ((int)blockIdx.x - BINS) * 4 + (threadIdx.x >> 6);
    const int nw = LN_BLOCKS * 4;
    float bias = b1[lane];
    float g0 = gamma[lane];
    float be0 = beta[lane];
    float g1 = (lane < 36) ? gamma[64 + lane] : 0.f;
    float be1 = (lane < 36) ? beta[64 + lane] : 0.f;
    for (int n = wid; n < N_NODES_C; n += nw) {
      const float* xr = x + (size_t)n * 100;
      float x0 = xr[lane];
      float x1 = (lane < 36) ? xr[64 + lane] : 0.f;
      x0 = fminf(fmaxf(x0, -CLAMP_C), CLAMP_C);
      x1 = fminf(fmaxf(x1, -CLAMP_C), CLAMP_C);
      float mu = wave_sum(x0 + x1) * 0.01f;
      float d0 = x0 - mu;
      float d1 = (lane < 36) ? (x1 - mu) : 0.f;
      float var = wave_sum(d0 * d0 + d1 * d1) * 0.01f;
      float inv = rsqrtf(var + LN_EPS_C);
      float xn0 = d0 * inv * g0 + be0;
      float xn1 = d1 * inv * g1 + be1;
      float acc = bias;
#pragma unroll
      for (int k = 0; k < 64; ++k) acc = fmaf(readlane_f(xn0, k), W1[k * 64 + lane], acc);
#pragma unroll
      for (int k = 0; k < 36; ++k) acc = fmaf(readlane_f(xn1, k), W1[(64 + k) * 64 + lane], acc);
      y[(size_t)n * 64 + lane] = f2bf(acc);
    }
  }
}

// ---------------- SpMM (bf16 gather, 16-way ILP) + ELU + GEMM(64->DOUT) ------
// Round-13 known-good structure: VGPR ~64, occupancy ~43%. Both more VGPRs
// (dual-row, r12: 282us) and fewer (forced 32 -> scratch spill, r15: 520us)
// are large regressions.
template <int DOUT>
__global__ __launch_bounds__(256) void spmm_elu_gemm_kernel(
    const int* __restrict__ rowstart, const int* __restrict__ counts,
    const int2* __restrict__ edges_s, const ushort_t* __restrict__ yb,
    const float* __restrict__ W, const float* __restrict__ b,
    ushort_t* __restrict__ out) {
  int lane = threadIdx.x & 63;
  int wid = blockIdx.x * (blockDim.x >> 6) + (threadIdx.x >> 6);
  int nw = gridDim.x * (blockDim.x >> 6);
  float w[64];
#pragma unroll
  for (int k = 0; k < 64; ++k) w[k] = (lane < DOUT) ? W[k * DOUT + lane] : 0.f;
  float bias = (lane < DOUT) ? b[lane] : 0.f;
  for (int n = wid; n < N_NODES_C; n += nw) {
    int start = rowstart[n];
    int cnt = counts[n];
    float a[8];
#pragma unroll
    for (int u = 0; u < 8; ++u) a[u] = 0.f;
    for (int base = 0; base < cnt; base += 64) {
      int m = cnt - base;
      if (m > 64) m = 64;
      int2 ev = make_int2(0, 0);
      if (lane < m) ev = edges_s[start + base + lane];
      int mr = (m + 15) & ~15;
      for (int j = 0; j < mr; j += 16) {
        float g[16];
#pragma unroll
        for (int u = 0; u < 16; ++u)
          g[u] = bf2f(yb[(size_t)__builtin_amdgcn_readlane(ev.x, j + u) * 64 + lane]);
#pragma unroll
        for (int u = 0; u < 16; ++u)
          a[u & 7] = fmaf(
              __uint_as_float(__builtin_amdgcn_readlane((unsigned)ev.y, j + u)), g[u],
              a[u & 7]);
      }
    }
    float acc = ((a[0] + a[1]) + (a[2] + a[3])) + ((a[4] + a[5]) + (a[6] + a[7]));
    // ELU
    float xe = (acc > 0.f) ? acc : expm1f(acc);
    // GEMM: out[n][lane] = bias + sum_k xe_k * W[k][lane]
    float o = bias;
#pragma unroll
    for (int k = 0; k < 64; ++k) o = fmaf(readlane_f(xe, k), w[k], o);
    if (lane < DOUT) out[(size_t)n * 64 + lane] = f2bf(o);
  }
}

// ---------------- final SpMM (bf16 gather, 16-way ILP, 47 valid) -> fp32 -----
__global__ __launch_bounds__(256) void spmm_final_kernel(
    const int* __restrict__ rowstart, const int* __restrict__ counts,
    const int2* __restrict__ edges_s, const ushort_t* __restrict__ yb,
    float* __restrict__ out) {
  int lane = threadIdx.x & 63;
  int wid = blockIdx.x * (blockDim.x >> 6) + (threadIdx.x >> 6);
  int nw = gridDim.x * (blockDim.x >> 6);
  int lmask = (lane < 47) ? lane : 46;  // OOB lanes stay inside the row; unused
  for (int n = wid; n < N_NODES_C; n += nw) {
    int start = rowstart[n];
    int cnt = counts[n];
    float a[8];
#pragma unroll
    for (int u = 0; u < 8; ++u) a[u] = 0.f;
    for (int base = 0; base < cnt; base += 64) {
      int m = cnt - base;
      if (m > 64) m = 64;
      int2 ev = make_int2(0, 0);
      if (lane < m) ev = edges_s[start + base + lane];
      int mr = (m + 15) & ~15;
      for (int j = 0; j < mr; j += 16) {
        float g[16];
#pragma unroll
        for (int u = 0; u < 16; ++u)
          g[u] = bf2f(yb[(size_t)__builtin_amdgcn_readlane(ev.x, j + u) * 64 + lmask]);
#pragma unroll
        for (int u = 0; u < 16; ++u)
          a[u & 7] = fmaf(
              __uint_as_float(__builtin_amdgcn_readlane((unsigned)ev.y, j + u)), g[u],
              a[u & 7]);
      }
    }
    float acc = ((a[0] + a[1]) + (a[2] + a[3])) + ((a[4] + a[5]) + (a[6] + a[7]));
    if (lane < 47) out[(size_t)n * 47 + lane] = acc;
  }
}

extern "C" void kernel_launch(void* const* d_in, const int* in_sizes, int n_in,
                              void* d_out, int out_size, void* d_ws, size_t ws_size,
                              hipStream_t stream) {
  const float* x = (const float*)d_in[0];
  const float* adj_vals = (const float*)d_in[1];
  const int* adj_row = (const int*)d_in[2];
  const int* adj_col = (const int*)d_in[3];
  const float* gamma = (const float*)d_in[4];
  const float* beta = (const float*)d_in[5];
  const float* W1 = (const float*)d_in[6];
  const float* b1 = (const float*)d_in[7];
  const float* W2 = (const float*)d_in[8];
  const float* b2 = (const float*)d_in[9];
  const float* W3 = (const float*)d_in[10];
  const float* b3 = (const float*)d_in[11];
  float* out = (float*)d_out;

  char* ws = (char*)d_ws;
  size_t off = 0;
  auto alloc = [&](size_t bytes) -> void* {
    void* p = ws + off;
    off += (bytes + 255) & ~(size_t)255;
    return p;
  };
  ushort_t* bufA = (ushort_t*)alloc(sizeof(ushort_t) * (size_t)N_NODES_C * 64);
  ushort_t* bufB = (ushort_t*)alloc(sizeof(ushort_t) * (size_t)N_NODES_C * 64);
  int* counts = (int*)alloc(sizeof(int) * N_NODES_C);
  int* cursor = (int*)alloc(sizeof(int) * N_NODES_C);
  int* rowstart = (int*)alloc(sizeof(int) * N_NODES_C);
  int* bsums = (int*)alloc(sizeof(int) * 256);
  int* bincur = (int*)alloc(sizeof(int) * 128);
  int2* edges_s = (int2*)alloc(sizeof(int2) * N_EDGES_C);
  int2* stage_cv = (int2*)alloc(sizeof(int2) * N_EDGES_C);
  ushort_t* stage_rlo = (ushort_t*)alloc(sizeof(ushort_t) * N_EDGES_C);

  hipMemsetAsync(counts, 0, sizeof(int) * N_NODES_C, stream);

  // 1.6M edges / (256 th * 8) = 782 blocks
  hist_kernel<<<782, 256, 0, stream>>>(adj_row, counts);
  int nb = (N_NODES_C + 1023) / 1024;  // 98
  scan1_kernel<<<nb, 256, 0, stream>>>(counts, rowstart, bsums);
  scan2_kernel<<<1, 128, 0, stream>>>(bsums, nb);
  scan3_kernel<<<nb, 256, 0, stream>>>(rowstart, cursor, bincur, bsums);

  // Pass A: radix-partition edges into bin-ordered staging (sequential runs)
  partition_kernel<<<NCHUNK, 256, 0, stream>>>(adj_row, adj_col, adj_vals, bincur,
                                               stage_cv, stage_rlo);
  // Pass B (98 bin-exclusive scatter blocks) + LN+GEMM1 (1024 blocks)
  binscatter_ln_kernel<<<BINS + LN_BLOCKS, 256, 0, stream>>>(
      rowstart, stage_cv, stage_rlo, cursor, edges_s, x, gamma, beta, W1, b1, bufA);

  // h2 = ELU(spmm(h1)) @ W2 + b2   (bf16 in/out, pitch 64)
  spmm_elu_gemm_kernel<64><<<2048, 256, 0, stream>>>(rowstart, counts, edges_s, bufA,
                                                     W2, b2, bufB);
  // h3 = ELU(spmm(h2)) @ W3 + b3   (bf16 in/out, pitch 64, 47 valid)
  spmm_elu_gemm_kernel<47><<<2048, 256, 0, stream>>>(rowstart, counts, edges_s, bufB,
                                                     W3, b3, bufA);
  // out = spmm(h3)  (fp32 out)
  spmm_final_kernel<<<2048, 256, 0, stream>>>(rowstart, counts, edges_s, bufA, out);
}